// Round 1
// baseline (2692.111 us; speedup 1.0000x reference)
//
#include <hip/hip_runtime.h>
#include <math.h>

typedef short bf16x8 __attribute__((ext_vector_type(8)));
typedef float f32x4 __attribute__((ext_vector_type(4)));
typedef unsigned short u16;

#define B_    32
#define D_    384
#define DEPTH 12
#define NST   16
#define DI_   768
#define R_    24
#define L_    196
#define NC_   1000
#define M_    (B_*L_)   // 6272

__device__ __forceinline__ u16 f2bf(float f) {
  union { float f; unsigned u; } v; v.f = f;
  unsigned r = v.u + 0x7fffu + ((v.u >> 16) & 1u);
  return (u16)(r >> 16);
}

// ---------------- weight prep ----------------
// transpose f32 (R rows, C cols) -> bf16 (C rows, R cols), batched over z
__global__ void k_transpose_bf16(const float* __restrict__ in, u16* __restrict__ out,
                                 int R, int C) {
  __shared__ float tile[32][33];
  const size_t zoff = (size_t)blockIdx.z * R * C;
  in  += zoff; out += zoff;
  int c0 = blockIdx.x * 32, r0 = blockIdx.y * 32;
  int tx = threadIdx.x, ty = threadIdx.y;
  for (int i = ty; i < 32; i += 8) {
    int r = r0 + i, c = c0 + tx;
    tile[i][tx] = (r < R && c < C) ? in[(size_t)r * C + c] : 0.f;
  }
  __syncthreads();
  for (int i = ty; i < 32; i += 8) {
    int c = c0 + i, r = r0 + tx;
    if (c < C && r < R) out[(size_t)c * R + r] = f2bf(tile[tx][i]);
  }
}

__global__ void k_convert_bf16(const float* __restrict__ in, u16* __restrict__ out, int n) {
  int i = blockIdx.x * 256 + threadIdx.x;
  if (i < n) out[i] = f2bf(in[i]);
}

// ---------------- im2col for patch embed ----------------
__global__ void k_im2col(const float* __restrict__ x, u16* __restrict__ xcol) {
  int idx = blockIdx.x * 256 + threadIdx.x;     // over M_*768
  if (idx >= M_ * 768) return;
  int k = idx % 768, m = idx / 768;
  int b = m / L_, l = m % L_;
  int li = l / 14, lj = l % 14;
  int c = k / 256, r = k % 256;
  int i = r / 16, j = r % 16;
  int hh = li * 16 + i, ww = lj * 16 + j;
  xcol[idx] = f2bf(x[(((size_t)b * 3 + c) * 224 + hh) * 224 + ww]);
}

// ---------------- GEMM: C(MxN) = A(MxK,bf16) * BT(NxK,bf16)^T ----------------
// EPI: 0 = store, 1 = add (residual), 2 = store + bias[col] + pos[(row%L)*N+col]
template<int EPI>
__global__ __launch_bounds__(256)
void k_gemm(const u16* __restrict__ A, const u16* __restrict__ BT,
            float* __restrict__ Cout, int Nn, int Kk,
            const float* __restrict__ bias, const float* __restrict__ pos) {
  const int m0 = blockIdx.x * 128;
  const int n0 = blockIdx.y * 128;
  __shared__ u16 lA[128 * 72];
  __shared__ u16 lB[128 * 72];
  const int tid  = threadIdx.x;
  const int wave = tid >> 6, lane = tid & 63;
  const int wm = (wave >> 1) * 64, wn = (wave & 1) * 64;
  f32x4 acc[4][4] = {};

  const int srow = tid >> 1;            // 0..127
  const int sk   = (tid & 1) * 32;      // 0 or 32
  const u16* gA = A  + (size_t)(m0 + srow) * Kk + sk;
  const u16* gB = BT + (size_t)(n0 + srow) * Kk + sk;
  const bool bvalid = (n0 + srow) < Nn;
  const int fr = lane & 15, kg = (lane >> 4) * 8;

  for (int k0 = 0; k0 < Kk; k0 += 64) {
    bf16x8 a[4], b[4] = {{}, {}, {}, {}};
    #pragma unroll
    for (int q = 0; q < 4; ++q) a[q] = *(const bf16x8*)(gA + k0 + q * 8);
    if (bvalid) {
      #pragma unroll
      for (int q = 0; q < 4; ++q) b[q] = *(const bf16x8*)(gB + k0 + q * 8);
    }
    __syncthreads();
    #pragma unroll
    for (int q = 0; q < 4; ++q) {
      *(bf16x8*)(lA + srow * 72 + sk + q * 8) = a[q];
      *(bf16x8*)(lB + srow * 72 + sk + q * 8) = b[q];
    }
    __syncthreads();
    #pragma unroll
    for (int kk = 0; kk < 64; kk += 32) {
      bf16x8 af[4], bf[4];
      #pragma unroll
      for (int i = 0; i < 4; ++i)
        af[i] = *(const bf16x8*)(lA + (wm + i * 16 + fr) * 72 + kk + kg);
      #pragma unroll
      for (int j = 0; j < 4; ++j)
        bf[j] = *(const bf16x8*)(lB + (wn + j * 16 + fr) * 72 + kk + kg);
      #pragma unroll
      for (int i = 0; i < 4; ++i)
        #pragma unroll
        for (int j = 0; j < 4; ++j)
          acc[i][j] = __builtin_amdgcn_mfma_f32_16x16x32_bf16(af[i], bf[j], acc[i][j], 0, 0, 0);
    }
  }

  const int rg = (lane >> 4) * 4;
  #pragma unroll
  for (int i = 0; i < 4; ++i) {
    int row = m0 + wm + i * 16 + rg;
    #pragma unroll
    for (int j = 0; j < 4; ++j) {
      int col = n0 + wn + j * 16 + fr;
      if (col >= Nn) continue;
      #pragma unroll
      for (int r = 0; r < 4; ++r) {
        float v = acc[i][j][r];
        size_t idx = (size_t)(row + r) * Nn + col;
        if (EPI == 0)      Cout[idx] = v;
        else if (EPI == 1) Cout[idx] += v;
        else               Cout[idx] = v + bias[col] + pos[(size_t)((row + r) % L_) * Nn + col];
      }
    }
  }
}

// ---------------- LayerNorm (writes bf16 for GEMM A) ----------------
__global__ __launch_bounds__(384)
void k_ln(const float* __restrict__ x, const float* __restrict__ g,
          const float* __restrict__ bt, u16* __restrict__ h) {
  const int m = blockIdx.x, d = threadIdx.x;
  __shared__ float red[12];
  float v = x[(size_t)m * D_ + d];
  float s = v, s2 = v * v;
  #pragma unroll
  for (int o = 32; o > 0; o >>= 1) { s += __shfl_xor(s, o); s2 += __shfl_xor(s2, o); }
  int wid = d >> 6;
  if ((d & 63) == 0) { red[wid] = s; red[6 + wid] = s2; }
  __syncthreads();
  float ts = 0.f, ts2 = 0.f;
  #pragma unroll
  for (int w = 0; w < 6; ++w) { ts += red[w]; ts2 += red[6 + w]; }
  float mu = ts / (float)D_;
  float var = ts2 / (float)D_ - mu * mu;
  float rs = rsqrtf(var + 1e-5f);
  h[(size_t)m * D_ + d] = f2bf((v - mu) * rs * g[d] + bt[d]);
}

// ---------------- causal depthwise conv (K=4) + SiLU ----------------
__global__ __launch_bounds__(256)
void k_conv(const float* __restrict__ xz, const float* __restrict__ cw,
            const float* __restrict__ cb, float* __restrict__ xc, u16* __restrict__ xcb) {
  int idx = blockIdx.x * 256 + threadIdx.x;   // over M_*DI_
  if (idx >= M_ * DI_) return;
  int di = idx % DI_, m = idx / DI_, l = m % L_;
  float w0 = cw[di * 4 + 0], w1 = cw[di * 4 + 1], w2 = cw[di * 4 + 2], w3 = cw[di * 4 + 3];
  const float* base = xz + (size_t)m * 1536 + di;
  float acc = cb[di] + w3 * base[0];
  if (l >= 1) acc += w2 * base[-1536];
  if (l >= 2) acc += w1 * base[-2 * 1536];
  if (l >= 3) acc += w0 * base[-3 * 1536];
  float s = acc / (1.f + __expf(-acc));       // silu
  xc[idx] = s;
  xcb[idx] = f2bf(s);
}

// ---------------- dt = softplus(dbc[:, :24] @ dtp_w + dtp_b) ----------------
__global__ __launch_bounds__(256)
void k_dt(const float* __restrict__ dbc, const float* __restrict__ dtw,
          const float* __restrict__ dtb, float* __restrict__ dt) {
  const int m0 = blockIdx.x * 32;
  const int di = blockIdx.y * 256 + threadIdx.x;
  __shared__ float sd[32][25];
  int lm = threadIdx.x >> 3, r8 = threadIdx.x & 7;
  #pragma unroll
  for (int q = 0; q < 3; ++q) {
    int r = r8 * 3 + q;
    sd[lm][r] = dbc[(size_t)(m0 + lm) * 56 + r];
  }
  __syncthreads();
  float w[24];
  #pragma unroll
  for (int r = 0; r < 24; ++r) w[r] = dtw[r * DI_ + di];
  const float bv = dtb[di];
  for (int mi = 0; mi < 32; ++mi) {
    float acc = bv;
    #pragma unroll
    for (int r = 0; r < 24; ++r) acc += sd[mi][r] * w[r];
    float sp = (acc > 20.f) ? acc : log1pf(__expf(acc));
    dt[(size_t)(m0 + mi) * DI_ + di] = sp;
  }
}

// ---------------- selective scan (sequential over L), gated, writes y bf16 ----------------
// grid (B_, DI_/64), block 256: thread = (di_local 0..63) x (nq 0..3), 4 states each
__global__ __launch_bounds__(256)
void k_scan(const float* __restrict__ dbc, const float* __restrict__ dt,
            const float* __restrict__ xc, const float* __restrict__ xz,
            const float* __restrict__ A_log, const float* __restrict__ Dsk,
            u16* __restrict__ yb) {
  const int b   = blockIdx.x;
  const int dil = threadIdx.x >> 2;
  const int nq  = threadIdx.x & 3;
  const int di  = blockIdx.y * 64 + dil;
  float Arow[4];
  #pragma unroll
  for (int n = 0; n < 4; ++n) Arow[n] = -__expf(A_log[di * NST + nq * 4 + n]);
  const float Dv = Dsk[di];
  float h[4] = {0.f, 0.f, 0.f, 0.f};
  __shared__ float sBC[8][32];
  const size_t mb = (size_t)b * L_;
  float dtc = dt[mb * DI_ + di];
  float xcc = xc[mb * DI_ + di];
  float zc  = xz[mb * 1536 + DI_ + di];
  for (int l = 0; l < L_; ++l) {
    if ((l & 7) == 0) {
      __syncthreads();
      int lc = threadIdx.x >> 5, c = threadIdx.x & 31;
      if (l + lc < L_) sBC[lc][c] = dbc[(mb + l + lc) * 56 + 24 + c];
      __syncthreads();
    }
    float dtn = 0.f, xcn = 0.f, zn = 0.f;
    if (l + 1 < L_) {
      size_t m1 = mb + l + 1;
      dtn = dt[m1 * DI_ + di];
      xcn = xc[m1 * DI_ + di];
      zn  = xz[m1 * 1536 + DI_ + di];
    }
    const int t = l & 7;
    float dx = dtc * xcc;
    float y = (nq == 0) ? Dv * xcc : 0.f;
    #pragma unroll
    for (int n = 0; n < 4; ++n) {
      float e = __expf(dtc * Arow[n]);
      h[n] = e * h[n] + dx * sBC[t][nq * 4 + n];
      y += h[n] * sBC[t][16 + nq * 4 + n];
    }
    y += __shfl_xor(y, 1);
    y += __shfl_xor(y, 2);
    if (nq == 0) {
      float sz = zc / (1.f + __expf(-zc));
      yb[(mb + l) * DI_ + di] = f2bf(y * sz);
    }
    dtc = dtn; xcc = xcn; zc = zn;
  }
}

// ---------------- final LN + mean over L ----------------
__global__ __launch_bounds__(384)
void k_final_feat(const float* __restrict__ x, const float* __restrict__ g,
                  const float* __restrict__ bt, float* __restrict__ feat) {
  const int b = blockIdx.x, d = threadIdx.x;
  __shared__ float red[12];
  float acc = 0.f;
  for (int l = 0; l < L_; ++l) {
    float v = x[((size_t)b * L_ + l) * D_ + d];
    float s = v, s2 = v * v;
    #pragma unroll
    for (int o = 32; o > 0; o >>= 1) { s += __shfl_xor(s, o); s2 += __shfl_xor(s2, o); }
    int wid = d >> 6;
    if ((d & 63) == 0) { red[wid] = s; red[6 + wid] = s2; }
    __syncthreads();
    float ts = 0.f, ts2 = 0.f;
    #pragma unroll
    for (int w = 0; w < 6; ++w) { ts += red[w]; ts2 += red[6 + w]; }
    float mu = ts / (float)D_;
    float var = ts2 / (float)D_ - mu * mu;
    acc += (v - mu) * rsqrtf(var + 1e-5f);
    __syncthreads();
  }
  feat[(size_t)b * D_ + d] = g[d] * (acc / (float)L_) + bt[d];
}

// ---------------- head ----------------
__global__ __launch_bounds__(256)
void k_head(const float* __restrict__ feat, const float* __restrict__ hw,
            const float* __restrict__ hb, float* __restrict__ out) {
  const int b = blockIdx.y;
  const int c = blockIdx.x * 256 + threadIdx.x;
  __shared__ float sf[D_];
  for (int i = threadIdx.x; i < D_; i += 256) sf[i] = feat[(size_t)b * D_ + i];
  __syncthreads();
  if (c >= NC_) return;
  float acc = hb[c];
  for (int d = 0; d < D_; ++d) acc += sf[d] * hw[(size_t)d * NC_ + c];
  out[(size_t)b * NC_ + c] = acc;
}

// =====================================================================
extern "C" void kernel_launch(void* const* d_in, const int* in_sizes, int n_in,
                              void* d_out, int out_size, void* d_ws, size_t ws_size,
                              hipStream_t stream) {
  const float* x_in    = (const float*)d_in[0];
  const float* patch_w = (const float*)d_in[1];
  const float* patch_b = (const float*)d_in[2];
  const float* pos     = (const float*)d_in[3];
  const float* bn_g    = (const float*)d_in[4];
  const float* bn_b    = (const float*)d_in[5];
  const float* in_w    = (const float*)d_in[6];
  const float* conv_w  = (const float*)d_in[7];
  const float* conv_b  = (const float*)d_in[8];
  const float* xp_w    = (const float*)d_in[9];
  const float* dtp_w   = (const float*)d_in[10];
  const float* dtp_b   = (const float*)d_in[11];
  const float* A_log   = (const float*)d_in[12];
  const float* D_skip  = (const float*)d_in[13];
  const float* out_w   = (const float*)d_in[14];
  const float* norm_g  = (const float*)d_in[15];
  const float* norm_b  = (const float*)d_in[16];
  const float* head_w  = (const float*)d_in[17];
  const float* head_b  = (const float*)d_in[18];
  float* out = (float*)d_out;

  char* ws = (char*)d_ws;
  size_t off = 0;
  auto alloc = [&](size_t bytes) { size_t o = off; off += (bytes + 255) & ~(size_t)255; return o; };

  float* xbuf   = (float*)(ws + alloc((size_t)M_ * D_ * 4));
  u16*   hbuf   = (u16*)  (ws + alloc((size_t)M_ * D_ * 2));
  float* xzbuf  = (float*)(ws + alloc((size_t)M_ * 1536 * 4));
  float* xcbuf  = (float*)(ws + alloc((size_t)M_ * DI_ * 4));
  u16*   xcbb   = (u16*)  (ws + alloc((size_t)M_ * DI_ * 2));
  float* dbcbuf = (float*)(ws + alloc((size_t)M_ * 56 * 4));
  float* dtbuf  = (float*)(ws + alloc((size_t)M_ * DI_ * 4));   // also aliased as im2col (bf16)
  u16*   ybuf   = (u16*)  (ws + alloc((size_t)M_ * DI_ * 2));
  float* feat   = (float*)(ws + alloc((size_t)B_ * D_ * 4));
  u16*   in_wT  = (u16*)  (ws + alloc((size_t)DEPTH * 1536 * D_ * 2));
  u16*   xp_wT  = (u16*)  (ws + alloc((size_t)DEPTH * 56 * DI_ * 2));
  u16*   out_wT = (u16*)  (ws + alloc((size_t)DEPTH * D_ * DI_ * 2));
  u16*   pw_b   = (u16*)  (ws + alloc((size_t)D_ * 768 * 2));
  u16*   im2col = (u16*)dtbuf;   // alias: used only before the block loop

  dim3 tb(32, 8);
  // weight prep
  k_transpose_bf16<<<dim3(48, 12, DEPTH), tb, 0, stream>>>(in_w,  in_wT,  D_, 1536);
  k_transpose_bf16<<<dim3(2, 24, DEPTH),  tb, 0, stream>>>(xp_w,  xp_wT,  DI_, 56);
  k_transpose_bf16<<<dim3(12, 24, DEPTH), tb, 0, stream>>>(out_w, out_wT, DI_, D_);
  k_convert_bf16<<<(D_ * 768 + 255) / 256, 256, 0, stream>>>(patch_w, pw_b, D_ * 768);

  // patch embed
  k_im2col<<<(M_ * 768 + 255) / 256, 256, 0, stream>>>(x_in, im2col);
  k_gemm<2><<<dim3(M_ / 128, D_ / 128), 256, 0, stream>>>(im2col, pw_b, xbuf, D_, 768, patch_b, pos);

  for (int dp = 0; dp < DEPTH; ++dp) {
    const u16* iwt = in_wT  + (size_t)dp * 1536 * D_;
    const u16* xwt = xp_wT  + (size_t)dp * 56 * DI_;
    const u16* owt = out_wT + (size_t)dp * D_ * DI_;
    k_ln<<<M_, 384, 0, stream>>>(xbuf, bn_g + dp * D_, bn_b + dp * D_, hbuf);
    k_gemm<0><<<dim3(M_ / 128, 1536 / 128), 256, 0, stream>>>(hbuf, iwt, xzbuf, 1536, D_, nullptr, nullptr);
    k_conv<<<(M_ * DI_ + 255) / 256, 256, 0, stream>>>(xzbuf, conv_w + (size_t)dp * DI_ * 4,
                                                       conv_b + dp * DI_, xcbuf, xcbb);
    k_gemm<0><<<dim3(M_ / 128, 1), 256, 0, stream>>>(xcbb, xwt, dbcbuf, 56, DI_, nullptr, nullptr);
    k_dt<<<dim3(M_ / 32, DI_ / 256), 256, 0, stream>>>(dbcbuf, dtp_w + (size_t)dp * R_ * DI_,
                                                       dtp_b + dp * DI_, dtbuf);
    k_scan<<<dim3(B_, DI_ / 64), 256, 0, stream>>>(dbcbuf, dtbuf, xcbuf, xzbuf,
                                                   A_log + (size_t)dp * DI_ * NST,
                                                   D_skip + dp * DI_, ybuf);
    k_gemm<1><<<dim3(M_ / 128, D_ / 128), 256, 0, stream>>>(ybuf, owt, xbuf, D_, DI_, nullptr, nullptr);
  }

  k_final_feat<<<B_, 384, 0, stream>>>(xbuf, norm_g, norm_b, feat);
  k_head<<<dim3((NC_ + 255) / 256, B_), 256, 0, stream>>>(feat, head_w, head_b, out);
}

// Round 2
// 2305.698 us; speedup vs baseline: 1.1676x; 1.1676x over previous
//
#include <hip/hip_runtime.h>
#include <math.h>

typedef short bf16x8 __attribute__((ext_vector_type(8)));
typedef float f32x4 __attribute__((ext_vector_type(4)));
typedef unsigned short u16;
typedef unsigned int u32;

#define B_    32
#define D_    384
#define DEPTH 12
#define NST   16
#define DI_   768
#define R_    24
#define L_    196
#define NC_   1000
#define M_    (B_*L_)   // 6272
#define SCH   32        // scan chunk length

__device__ __forceinline__ u16 f2bf(float f) {
  union { float f; unsigned u; } v; v.f = f;
  unsigned r = v.u + 0x7fffu + ((v.u >> 16) & 1u);
  return (u16)(r >> 16);
}

// ---------------- weight prep ----------------
__global__ void k_transpose_bf16(const float* __restrict__ in, u16* __restrict__ out,
                                 int R, int C) {
  __shared__ float tile[32][33];
  const size_t zoff = (size_t)blockIdx.z * R * C;
  in  += zoff; out += zoff;
  int c0 = blockIdx.x * 32, r0 = blockIdx.y * 32;
  int tx = threadIdx.x, ty = threadIdx.y;
  for (int i = ty; i < 32; i += 8) {
    int r = r0 + i, c = c0 + tx;
    tile[i][tx] = (r < R && c < C) ? in[(size_t)r * C + c] : 0.f;
  }
  __syncthreads();
  for (int i = ty; i < 32; i += 8) {
    int c = c0 + i, r = r0 + tx;
    if (c < C && r < R) out[(size_t)c * R + r] = f2bf(tile[tx][i]);
  }
}

__global__ void k_convert_bf16(const float* __restrict__ in, u16* __restrict__ out, int n) {
  int i = blockIdx.x * 256 + threadIdx.x;
  if (i < n) out[i] = f2bf(in[i]);
}

// ---------------- im2col for patch embed ----------------
__global__ void k_im2col(const float* __restrict__ x, u16* __restrict__ xcol) {
  int idx = blockIdx.x * 256 + threadIdx.x;     // over M_*768
  if (idx >= M_ * 768) return;
  int k = idx % 768, m = idx / 768;
  int b = m / L_, l = m % L_;
  int li = l / 14, lj = l % 14;
  int c = k / 256, r = k % 256;
  int i = r / 16, j = r % 16;
  int hh = li * 16 + i, ww = lj * 16 + j;
  xcol[idx] = f2bf(x[(((size_t)b * 3 + c) * 224 + hh) * 224 + ww]);
}

// ---------------- GEMM: C(MxN) = A(MxK,bf16) * BT(NxK,bf16)^T ----------------
// EPI: 0 = store, 1 = add (residual), 2 = store + bias[col] + pos[(row%L)*N+col]
// 256 threads = 4 waves arranged 2x2; wave tile (BM/2)x(BN/2); acc[BM/32][BN/32]
template<int BM, int BN, int EPI>
__global__ __launch_bounds__(256)
void k_gemm(const u16* __restrict__ A, const u16* __restrict__ BT,
            float* __restrict__ Cout, int Nn, int Kk,
            const float* __restrict__ bias, const float* __restrict__ pos) {
  const int m0 = blockIdx.x * BM;
  const int n0 = blockIdx.y * BN;
  __shared__ u16 lA[BM * 72];
  __shared__ u16 lB[BN * 72];
  const int tid  = threadIdx.x;
  const int wave = tid >> 6, lane = tid & 63;
  const int wm = (wave >> 1) * (BM / 2), wn = (wave & 1) * (BN / 2);
  constexpr int MI = BM / 32, NJ = BN / 32;
  constexpr int NV = (BM + BN) / 32;     // bf16x8 loads per thread per k-chunk
  f32x4 acc[MI][NJ] = {};
  const int fr = lane & 15, kg = (lane >> 4) * 8;

  for (int k0 = 0; k0 < Kk; k0 += 64) {
    bf16x8 v[NV];
    #pragma unroll
    for (int q = 0; q < NV; ++q) {
      int id = tid + q * 256;
      int row = id >> 3, vv = id & 7;
      bf16x8 t = {};
      if (row < BM) {
        t = *(const bf16x8*)(A + (size_t)(m0 + row) * Kk + k0 + vv * 8);
      } else {
        int br = n0 + row - BM;
        if (br < Nn) t = *(const bf16x8*)(BT + (size_t)br * Kk + k0 + vv * 8);
      }
      v[q] = t;
    }
    __syncthreads();
    #pragma unroll
    for (int q = 0; q < NV; ++q) {
      int id = tid + q * 256;
      int row = id >> 3, vv = id & 7;
      u16* dst = (row < BM) ? (lA + row * 72 + vv * 8) : (lB + (size_t)(row - BM) * 72 + vv * 8);
      *(bf16x8*)dst = v[q];
    }
    __syncthreads();
    #pragma unroll
    for (int kk = 0; kk < 64; kk += 32) {
      bf16x8 af[MI], bfr[NJ];
      #pragma unroll
      for (int i = 0; i < MI; ++i)
        af[i] = *(const bf16x8*)(lA + (wm + i * 16 + fr) * 72 + kk + kg);
      #pragma unroll
      for (int j = 0; j < NJ; ++j)
        bfr[j] = *(const bf16x8*)(lB + (wn + j * 16 + fr) * 72 + kk + kg);
      #pragma unroll
      for (int i = 0; i < MI; ++i)
        #pragma unroll
        for (int j = 0; j < NJ; ++j)
          acc[i][j] = __builtin_amdgcn_mfma_f32_16x16x32_bf16(af[i], bfr[j], acc[i][j], 0, 0, 0);
    }
  }

  const int rg = (lane >> 4) * 4;
  #pragma unroll
  for (int i = 0; i < MI; ++i) {
    int row = m0 + wm + i * 16 + rg;
    #pragma unroll
    for (int j = 0; j < NJ; ++j) {
      int col = n0 + wn + j * 16 + fr;
      if (col >= Nn) continue;
      #pragma unroll
      for (int r = 0; r < 4; ++r) {
        float v = acc[i][j][r];
        size_t idx = (size_t)(row + r) * Nn + col;
        if (EPI == 0)      Cout[idx] = v;
        else if (EPI == 1) Cout[idx] += v;
        else               Cout[idx] = v + bias[col] + pos[(size_t)((row + r) % L_) * Nn + col];
      }
    }
  }
}

// ---------------- LayerNorm (writes bf16 for GEMM A) ----------------
__global__ __launch_bounds__(384)
void k_ln(const float* __restrict__ x, const float* __restrict__ g,
          const float* __restrict__ bt, u16* __restrict__ h) {
  const int m = blockIdx.x, d = threadIdx.x;
  __shared__ float red[12];
  float v = x[(size_t)m * D_ + d];
  float s = v, s2 = v * v;
  #pragma unroll
  for (int o = 32; o > 0; o >>= 1) { s += __shfl_xor(s, o); s2 += __shfl_xor(s2, o); }
  int wid = d >> 6;
  if ((d & 63) == 0) { red[wid] = s; red[6 + wid] = s2; }
  __syncthreads();
  float ts = 0.f, ts2 = 0.f;
  #pragma unroll
  for (int w = 0; w < 6; ++w) { ts += red[w]; ts2 += red[6 + w]; }
  float mu = ts / (float)D_;
  float var = ts2 / (float)D_ - mu * mu;
  float rs = rsqrtf(var + 1e-5f);
  h[(size_t)m * D_ + d] = f2bf((v - mu) * rs * g[d] + bt[d]);
}

// ---------------- causal depthwise conv (K=4) + SiLU ----------------
__global__ __launch_bounds__(256)
void k_conv(const float* __restrict__ xz, const float* __restrict__ cw,
            const float* __restrict__ cb, float* __restrict__ xc, u16* __restrict__ xcb) {
  int idx = blockIdx.x * 256 + threadIdx.x;   // over M_*DI_
  if (idx >= M_ * DI_) return;
  int di = idx % DI_, m = idx / DI_, l = m % L_;
  float w0 = cw[di * 4 + 0], w1 = cw[di * 4 + 1], w2 = cw[di * 4 + 2], w3 = cw[di * 4 + 3];
  const float* base = xz + (size_t)m * 1536 + di;
  float acc = cb[di] + w3 * base[0];
  if (l >= 1) acc += w2 * base[-1536];
  if (l >= 2) acc += w1 * base[-2 * 1536];
  if (l >= 3) acc += w0 * base[-3 * 1536];
  float s = acc / (1.f + __expf(-acc));       // silu
  xc[idx] = s;
  xcb[idx] = f2bf(s);
}

// ---------------- dt = softplus(dbc[:, :24] @ dtp_w + dtp_b) ----------------
__global__ __launch_bounds__(256)
void k_dt(const float* __restrict__ dbc, const float* __restrict__ dtw,
          const float* __restrict__ dtb, float* __restrict__ dt) {
  const int m0 = blockIdx.x * 32;
  const int di = blockIdx.y * 256 + threadIdx.x;
  __shared__ float sd[32][25];
  int lm = threadIdx.x >> 3, r8 = threadIdx.x & 7;
  #pragma unroll
  for (int q = 0; q < 3; ++q) {
    int r = r8 * 3 + q;
    sd[lm][r] = dbc[(size_t)(m0 + lm) * 56 + r];
  }
  __syncthreads();
  float w[24];
  #pragma unroll
  for (int r = 0; r < 24; ++r) w[r] = dtw[r * DI_ + di];
  const float bv = dtb[di];
  for (int mi = 0; mi < 32; ++mi) {
    float acc = bv;
    #pragma unroll
    for (int r = 0; r < 24; ++r) acc += sd[mi][r] * w[r];
    float sp = (acc > 20.f) ? acc : log1pf(__expf(acc));
    dt[(size_t)(m0 + mi) * DI_ + di] = sp;
  }
}

// ---------------- selective scan v2: chunked LDS double-buffer ----------------
// grid (B_, DI_/64), block 256: thread = (di_local 0..63) x (nq 0..3), 4 states each
__global__ __launch_bounds__(256)
void k_scan(const float* __restrict__ dbc, const float* __restrict__ dt,
            const float* __restrict__ xc, const float* __restrict__ xz,
            const float* __restrict__ A_log, const float* __restrict__ Dsk,
            u16* __restrict__ yb) {
  const int b   = blockIdx.x;
  const int di0 = blockIdx.y * 64;
  const int tid = threadIdx.x;
  const int dil = tid >> 2, nq = tid & 3;
  const int di  = di0 + dil;
  __shared__ float sDT[2][SCH][64];
  __shared__ float sXC[2][SCH][64];
  __shared__ float sZ [2][SCH][64];
  __shared__ float sBC[2][SCH][32];
  __shared__ u16  sY [SCH][64];

  float Arow[4];
  #pragma unroll
  for (int n = 0; n < 4; ++n) Arow[n] = -__expf(A_log[di * NST + nq * 4 + n]);
  const float Dv = Dsk[di];
  float h[4] = {0.f, 0.f, 0.f, 0.f};
  const size_t mb = (size_t)b * L_;

  const int r16 = tid >> 4, c16 = (tid & 15) * 4;   // 64-wide arrays, 2 rounds of 16 rows
  const int r8  = tid >> 3, c8  = (tid & 7) * 4;    // 32-wide BC, 1 round of 32 rows

  f32x4 pDT[2], pXC[2], pZ[2], pBC;
  auto issue = [&](int lb) {
    #pragma unroll
    for (int j = 0; j < 2; ++j) {
      int l = lb + r16 + j * 16;
      if (l < L_) {
        pDT[j] = *(const f32x4*)(dt + (mb + l) * DI_ + di0 + c16);
        pXC[j] = *(const f32x4*)(xc + (mb + l) * DI_ + di0 + c16);
        pZ[j]  = *(const f32x4*)(xz + (mb + l) * 1536 + DI_ + di0 + c16);
      } else { pDT[j] = {}; pXC[j] = {}; pZ[j] = {}; }
    }
    int l = lb + r8;
    if (l < L_) pBC = *(const f32x4*)(dbc + (mb + l) * 56 + 24 + c8);
    else        pBC = {};
  };
  auto store = [&](int buf) {
    #pragma unroll
    for (int j = 0; j < 2; ++j) {
      int row = r16 + j * 16;
      *(f32x4*)&sDT[buf][row][c16] = pDT[j];
      *(f32x4*)&sXC[buf][row][c16] = pXC[j];
      *(f32x4*)&sZ [buf][row][c16] = pZ[j];
    }
    *(f32x4*)&sBC[buf][r8][c8] = pBC;
  };

  issue(0); store(0); __syncthreads();
  const int nch = (L_ + SCH - 1) / SCH;   // 7
  for (int c = 0; c < nch; ++c) {
    const int lb = c * SCH;
    if (c + 1 < nch) issue(lb + SCH);     // global loads overlap compute below
    const int cur = c & 1;
    #pragma unroll 4
    for (int t = 0; t < SCH; ++t) {
      float dtc = sDT[cur][t][dil];
      float xcc = sXC[cur][t][dil];
      float dx = dtc * xcc;
      f32x4 Bv = *(const f32x4*)&sBC[cur][t][nq * 4];
      f32x4 Cv = *(const f32x4*)&sBC[cur][t][16 + nq * 4];
      float y = (nq == 0) ? Dv * xcc : 0.f;
      #pragma unroll
      for (int n = 0; n < 4; ++n) {
        float e = __expf(dtc * Arow[n]);
        h[n] = e * h[n] + dx * Bv[n];
        y += h[n] * Cv[n];
      }
      y += __shfl_xor(y, 1);
      y += __shfl_xor(y, 2);
      if (nq == 0) {
        float zc = sZ[cur][t][dil];
        float sz = zc / (1.f + __expf(-zc));
        sY[t][dil] = f2bf(y * sz);
      }
    }
    __syncthreads();
    #pragma unroll
    for (int j = 0; j < 4; ++j) {
      int id = tid + j * 256;
      int row = id >> 5, c2 = id & 31;
      int l = lb + row;
      if (l < L_)
        *((u32*)yb + ((mb + l) * DI_ + di0) / 2 + c2) = *((const u32*)&sY[row][0] + c2);
    }
    if (c + 1 < nch) store((c + 1) & 1);
    __syncthreads();
  }
}

// ---------------- final LN partial sums: grid (B_, 7), 28 rows each ----------------
__global__ __launch_bounds__(384)
void k_feat_part(const float* __restrict__ x, float* __restrict__ partial) {
  const int b = blockIdx.x, j = blockIdx.y, d = threadIdx.x;
  __shared__ float red[12];
  const int l0 = j * 28;
  float acc = 0.f;
  float v = x[((size_t)b * L_ + l0) * D_ + d];
  for (int l = l0; l < l0 + 28; ++l) {
    float vn = (l + 1 < l0 + 28) ? x[((size_t)b * L_ + l + 1) * D_ + d] : 0.f;
    float s = v, s2 = v * v;
    #pragma unroll
    for (int o = 32; o > 0; o >>= 1) { s += __shfl_xor(s, o); s2 += __shfl_xor(s2, o); }
    int wid = d >> 6;
    if ((d & 63) == 0) { red[wid] = s; red[6 + wid] = s2; }
    __syncthreads();
    float ts = 0.f, ts2 = 0.f;
    #pragma unroll
    for (int w = 0; w < 6; ++w) { ts += red[w]; ts2 += red[6 + w]; }
    float mu = ts * (1.f / (float)D_);
    float var = ts2 * (1.f / (float)D_) - mu * mu;
    acc += (v - mu) * rsqrtf(var + 1e-5f);
    __syncthreads();
    v = vn;
  }
  partial[((size_t)(b * 7 + j)) * D_ + d] = acc;
}

// ---------------- head (folds final-LN gamma/beta + mean) ----------------
__global__ __launch_bounds__(256)
void k_head(const float* __restrict__ partial, const float* __restrict__ g,
            const float* __restrict__ bt, const float* __restrict__ hw,
            const float* __restrict__ hb, float* __restrict__ out) {
  const int b = blockIdx.y;
  const int c = blockIdx.x * 256 + threadIdx.x;
  __shared__ float sf[D_];
  for (int i = threadIdx.x; i < D_; i += 256) {
    float s = 0.f;
    #pragma unroll
    for (int j = 0; j < 7; ++j) s += partial[((size_t)(b * 7 + j)) * D_ + i];
    sf[i] = g[i] * (s * (1.f / (float)L_)) + bt[i];
  }
  __syncthreads();
  if (c >= NC_) return;
  float acc = hb[c];
  for (int d = 0; d < D_; ++d) acc += sf[d] * hw[(size_t)d * NC_ + c];
  out[(size_t)b * NC_ + c] = acc;
}

// =====================================================================
extern "C" void kernel_launch(void* const* d_in, const int* in_sizes, int n_in,
                              void* d_out, int out_size, void* d_ws, size_t ws_size,
                              hipStream_t stream) {
  const float* x_in    = (const float*)d_in[0];
  const float* patch_w = (const float*)d_in[1];
  const float* patch_b = (const float*)d_in[2];
  const float* pos     = (const float*)d_in[3];
  const float* bn_g    = (const float*)d_in[4];
  const float* bn_b    = (const float*)d_in[5];
  const float* in_w    = (const float*)d_in[6];
  const float* conv_w  = (const float*)d_in[7];
  const float* conv_b  = (const float*)d_in[8];
  const float* xp_w    = (const float*)d_in[9];
  const float* dtp_w   = (const float*)d_in[10];
  const float* dtp_b   = (const float*)d_in[11];
  const float* A_log   = (const float*)d_in[12];
  const float* D_skip  = (const float*)d_in[13];
  const float* out_w   = (const float*)d_in[14];
  const float* norm_g  = (const float*)d_in[15];
  const float* norm_b  = (const float*)d_in[16];
  const float* head_w  = (const float*)d_in[17];
  const float* head_b  = (const float*)d_in[18];
  float* out = (float*)d_out;

  char* ws = (char*)d_ws;
  size_t off = 0;
  auto alloc = [&](size_t bytes) { size_t o = off; off += (bytes + 255) & ~(size_t)255; return o; };

  float* xbuf   = (float*)(ws + alloc((size_t)M_ * D_ * 4));
  u16*   hbuf   = (u16*)  (ws + alloc((size_t)M_ * D_ * 2));
  float* xzbuf  = (float*)(ws + alloc((size_t)M_ * 1536 * 4));
  float* xcbuf  = (float*)(ws + alloc((size_t)M_ * DI_ * 4));
  u16*   xcbb   = (u16*)  (ws + alloc((size_t)M_ * DI_ * 2));
  float* dbcbuf = (float*)(ws + alloc((size_t)M_ * 56 * 4));
  float* dtbuf  = (float*)(ws + alloc((size_t)M_ * DI_ * 4));   // aliased as im2col before loop
  u16*   ybuf   = (u16*)  (ws + alloc((size_t)M_ * DI_ * 2));
  float* partial= (float*)(ws + alloc((size_t)B_ * 7 * D_ * 4));
  u16*   in_wT  = (u16*)  (ws + alloc((size_t)DEPTH * 1536 * D_ * 2));
  u16*   xp_wT  = (u16*)  (ws + alloc((size_t)DEPTH * 56 * DI_ * 2));
  u16*   out_wT = (u16*)  (ws + alloc((size_t)DEPTH * D_ * DI_ * 2));
  u16*   pw_b   = (u16*)  (ws + alloc((size_t)D_ * 768 * 2));
  u16*   im2col = (u16*)dtbuf;

  dim3 tb(32, 8);
  k_transpose_bf16<<<dim3(48, 12, DEPTH), tb, 0, stream>>>(in_w,  in_wT,  D_, 1536);
  k_transpose_bf16<<<dim3(2, 24, DEPTH),  tb, 0, stream>>>(xp_w,  xp_wT,  DI_, 56);
  k_transpose_bf16<<<dim3(12, 24, DEPTH), tb, 0, stream>>>(out_w, out_wT, DI_, D_);
  k_convert_bf16<<<(D_ * 768 + 255) / 256, 256, 0, stream>>>(patch_w, pw_b, D_ * 768);

  k_im2col<<<(M_ * 768 + 255) / 256, 256, 0, stream>>>(x_in, im2col);
  k_gemm<64,128,2><<<dim3(M_ / 64, 3), 256, 0, stream>>>(im2col, pw_b, xbuf, D_, 768, patch_b, pos);

  for (int dp = 0; dp < DEPTH; ++dp) {
    const u16* iwt = in_wT  + (size_t)dp * 1536 * D_;
    const u16* xwt = xp_wT  + (size_t)dp * 56 * DI_;
    const u16* owt = out_wT + (size_t)dp * D_ * DI_;
    k_ln<<<M_, 384, 0, stream>>>(xbuf, bn_g + dp * D_, bn_b + dp * D_, hbuf);
    k_gemm<128,128,0><<<dim3(M_ / 128, 12), 256, 0, stream>>>(hbuf, iwt, xzbuf, 1536, D_, nullptr, nullptr);
    k_conv<<<(M_ * DI_ + 255) / 256, 256, 0, stream>>>(xzbuf, conv_w + (size_t)dp * DI_ * 4,
                                                       conv_b + dp * DI_, xcbuf, xcbb);
    k_gemm<32,64,0><<<dim3(M_ / 32, 1), 256, 0, stream>>>(xcbb, xwt, dbcbuf, 56, DI_, nullptr, nullptr);
    k_dt<<<dim3(M_ / 32, DI_ / 256), 256, 0, stream>>>(dbcbuf, dtp_w + (size_t)dp * R_ * DI_,
                                                       dtp_b + dp * DI_, dtbuf);
    k_scan<<<dim3(B_, DI_ / 64), 256, 0, stream>>>(dbcbuf, dtbuf, xcbuf, xzbuf,
                                                   A_log + (size_t)dp * DI_ * NST,
                                                   D_skip + dp * DI_, ybuf);
    k_gemm<64,128,1><<<dim3(M_ / 64, 3), 256, 0, stream>>>(ybuf, owt, xbuf, D_, DI_, nullptr, nullptr);
  }

  k_feat_part<<<dim3(B_, 7), 384, 0, stream>>>(xbuf, partial);
  k_head<<<dim3((NC_ + 255) / 256, B_), 256, 0, stream>>>(partial, norm_g, norm_b, head_w, head_b, out);
}

// Round 3
// 2083.057 us; speedup vs baseline: 1.2924x; 1.1069x over previous
//
#include <hip/hip_runtime.h>
#include <math.h>

typedef short bf16x8 __attribute__((ext_vector_type(8)));
typedef float f32x4 __attribute__((ext_vector_type(4)));
typedef unsigned short u16;
typedef unsigned int u32;

#define B_    32
#define D_    384
#define DEPTH 12
#define NST   16
#define DI_   768
#define R_    24
#define L_    196
#define NC_   1000
#define M_    (B_*L_)   // 6272
#define SCH   32        // scan chunk length

__device__ __forceinline__ u16 f2bf(float f) {
  union { float f; unsigned u; } v; v.f = f;
  unsigned r = v.u + 0x7fffu + ((v.u >> 16) & 1u);
  return (u16)(r >> 16);
}

// ---------------- weight prep ----------------
__global__ void k_transpose_bf16(const float* __restrict__ in, u16* __restrict__ out,
                                 int R, int C) {
  __shared__ float tile[32][33];
  const size_t zoff = (size_t)blockIdx.z * R * C;
  in  += zoff; out += zoff;
  int c0 = blockIdx.x * 32, r0 = blockIdx.y * 32;
  int tx = threadIdx.x, ty = threadIdx.y;
  for (int i = ty; i < 32; i += 8) {
    int r = r0 + i, c = c0 + tx;
    tile[i][tx] = (r < R && c < C) ? in[(size_t)r * C + c] : 0.f;
  }
  __syncthreads();
  for (int i = ty; i < 32; i += 8) {
    int c = c0 + i, r = r0 + tx;
    if (c < C && r < R) out[(size_t)c * R + r] = f2bf(tile[tx][i]);
  }
}

__global__ void k_convert_bf16(const float* __restrict__ in, u16* __restrict__ out, int n) {
  int i = blockIdx.x * 256 + threadIdx.x;
  if (i < n) out[i] = f2bf(in[i]);
}

// ---------------- im2col for patch embed ----------------
__global__ void k_im2col(const float* __restrict__ x, u16* __restrict__ xcol) {
  int idx = blockIdx.x * 256 + threadIdx.x;     // over M_*768
  if (idx >= M_ * 768) return;
  int k = idx % 768, m = idx / 768;
  int b = m / L_, l = m % L_;
  int li = l / 14, lj = l % 14;
  int c = k / 256, r = k % 256;
  int i = r / 16, j = r % 16;
  int hh = li * 16 + i, ww = lj * 16 + j;
  xcol[idx] = f2bf(x[(((size_t)b * 3 + c) * 224 + hh) * 224 + ww]);
}

// ---------------- GEMM: C(MxN) = A(MxK,bf16) * BT(NxK,bf16)^T ----------------
// EPI: 0 = store, 1 = add (residual), 2 = store + bias[col] + pos[(row%L)*N+col]
template<int BM, int BN, int EPI>
__global__ __launch_bounds__(256)
void k_gemm(const u16* __restrict__ A, const u16* __restrict__ BT,
            float* __restrict__ Cout, int Nn, int Kk,
            const float* __restrict__ bias, const float* __restrict__ pos) {
  const int m0 = blockIdx.x * BM;
  const int n0 = blockIdx.y * BN;
  __shared__ u16 lA[BM * 72];
  __shared__ u16 lB[BN * 72];
  const int tid  = threadIdx.x;
  const int wave = tid >> 6, lane = tid & 63;
  const int wm = (wave >> 1) * (BM / 2), wn = (wave & 1) * (BN / 2);
  constexpr int MI = BM / 32, NJ = BN / 32;
  constexpr int NV = (BM + BN) / 32;     // bf16x8 loads per thread per k-chunk
  f32x4 acc[MI][NJ] = {};
  const int fr = lane & 15, kg = (lane >> 4) * 8;

  for (int k0 = 0; k0 < Kk; k0 += 64) {
    bf16x8 v[NV];
    #pragma unroll
    for (int q = 0; q < NV; ++q) {
      int id = tid + q * 256;
      int row = id >> 3, vv = id & 7;
      bf16x8 t = {};
      if (row < BM) {
        t = *(const bf16x8*)(A + (size_t)(m0 + row) * Kk + k0 + vv * 8);
      } else {
        int br = n0 + row - BM;
        if (br < Nn) t = *(const bf16x8*)(BT + (size_t)br * Kk + k0 + vv * 8);
      }
      v[q] = t;
    }
    __syncthreads();
    #pragma unroll
    for (int q = 0; q < NV; ++q) {
      int id = tid + q * 256;
      int row = id >> 3, vv = id & 7;
      u16* dst = (row < BM) ? (lA + row * 72 + vv * 8) : (lB + (size_t)(row - BM) * 72 + vv * 8);
      *(bf16x8*)dst = v[q];
    }
    __syncthreads();
    #pragma unroll
    for (int kk = 0; kk < 64; kk += 32) {
      bf16x8 af[MI], bfr[NJ];
      #pragma unroll
      for (int i = 0; i < MI; ++i)
        af[i] = *(const bf16x8*)(lA + (wm + i * 16 + fr) * 72 + kk + kg);
      #pragma unroll
      for (int j = 0; j < NJ; ++j)
        bfr[j] = *(const bf16x8*)(lB + (wn + j * 16 + fr) * 72 + kk + kg);
      #pragma unroll
      for (int i = 0; i < MI; ++i)
        #pragma unroll
        for (int j = 0; j < NJ; ++j)
          acc[i][j] = __builtin_amdgcn_mfma_f32_16x16x32_bf16(af[i], bfr[j], acc[i][j], 0, 0, 0);
    }
  }

  const int rg = (lane >> 4) * 4;
  #pragma unroll
  for (int i = 0; i < MI; ++i) {
    int row = m0 + wm + i * 16 + rg;
    #pragma unroll
    for (int j = 0; j < NJ; ++j) {
      int col = n0 + wn + j * 16 + fr;
      if (col >= Nn) continue;
      #pragma unroll
      for (int r = 0; r < 4; ++r) {
        float v = acc[i][j][r];
        size_t idx = (size_t)(row + r) * Nn + col;
        if (EPI == 0)      Cout[idx] = v;
        else if (EPI == 1) Cout[idx] += v;
        else               Cout[idx] = v + bias[col] + pos[(size_t)((row + r) % L_) * Nn + col];
      }
    }
  }
}

// ---------------- LayerNorm (writes bf16 for GEMM A) ----------------
__global__ __launch_bounds__(384)
void k_ln(const float* __restrict__ x, const float* __restrict__ g,
          const float* __restrict__ bt, u16* __restrict__ h) {
  const int m = blockIdx.x, d = threadIdx.x;
  __shared__ float red[12];
  float v = x[(size_t)m * D_ + d];
  float s = v, s2 = v * v;
  #pragma unroll
  for (int o = 32; o > 0; o >>= 1) { s += __shfl_xor(s, o); s2 += __shfl_xor(s2, o); }
  int wid = d >> 6;
  if ((d & 63) == 0) { red[wid] = s; red[6 + wid] = s2; }
  __syncthreads();
  float ts = 0.f, ts2 = 0.f;
  #pragma unroll
  for (int w = 0; w < 6; ++w) { ts += red[w]; ts2 += red[6 + w]; }
  float mu = ts / (float)D_;
  float var = ts2 / (float)D_ - mu * mu;
  float rs = rsqrtf(var + 1e-5f);
  h[(size_t)m * D_ + d] = f2bf((v - mu) * rs * g[d] + bt[d]);
}

// ---------------- causal depthwise conv (K=4) + SiLU ----------------
__global__ __launch_bounds__(256)
void k_conv(const float* __restrict__ xz, const float* __restrict__ cw,
            const float* __restrict__ cb, float* __restrict__ xc, u16* __restrict__ xcb) {
  int idx = blockIdx.x * 256 + threadIdx.x;   // over M_*DI_
  if (idx >= M_ * DI_) return;
  int di = idx % DI_, m = idx / DI_, l = m % L_;
  float w0 = cw[di * 4 + 0], w1 = cw[di * 4 + 1], w2 = cw[di * 4 + 2], w3 = cw[di * 4 + 3];
  const float* base = xz + (size_t)m * 1536 + di;
  float acc = cb[di] + w3 * base[0];
  if (l >= 1) acc += w2 * base[-1536];
  if (l >= 2) acc += w1 * base[-2 * 1536];
  if (l >= 3) acc += w0 * base[-3 * 1536];
  float s = acc / (1.f + __expf(-acc));       // silu
  xc[idx] = s;
  xcb[idx] = f2bf(s);
}

// ---------------- dt = softplus(dbc[:, :24] @ dtp_w + dtp_b) ----------------
// latency-fixed: TM=16 rows/block (2x grid), 4 independent FMA chains via unroll,
// fast softplus (v_exp + v_log), padded LDS.
__global__ __launch_bounds__(256)
void k_dt(const float* __restrict__ dbc, const float* __restrict__ dtw,
          const float* __restrict__ dtb, float* __restrict__ dt) {
  const int m0 = blockIdx.x * 16;
  const int di = blockIdx.y * 256 + threadIdx.x;
  __shared__ float sd[16][25];
  #pragma unroll
  for (int q = 0; q < 2; ++q) {
    int id = threadIdx.x + q * 256;
    if (id < 16 * 24) {
      int r = id / 24, c = id % 24;
      sd[r][c] = dbc[(size_t)(m0 + r) * 56 + c];
    }
  }
  __syncthreads();
  float w[24];
  #pragma unroll
  for (int r = 0; r < 24; ++r) w[r] = dtw[r * DI_ + di];
  const float bv = dtb[di];
  #pragma unroll 4
  for (int mi = 0; mi < 16; ++mi) {
    float acc = bv;
    #pragma unroll
    for (int r = 0; r < 24; ++r) acc += sd[mi][r] * w[r];
    float e  = __expf(-fabsf(acc));
    float sp = fmaxf(acc, 0.f) + __logf(1.f + e);
    dt[(size_t)(m0 + mi) * DI_ + di] = sp;
  }
}

// ---------------- selective scan v2: chunked LDS double-buffer ----------------
// grid (B_, DI_/64), block 256: thread = (di_local 0..63) x (nq 0..3), 4 states each
__global__ __launch_bounds__(256)
void k_scan(const float* __restrict__ dbc, const float* __restrict__ dt,
            const float* __restrict__ xc, const float* __restrict__ xz,
            const float* __restrict__ A_log, const float* __restrict__ Dsk,
            u16* __restrict__ yb) {
  const int b   = blockIdx.x;
  const int di0 = blockIdx.y * 64;
  const int tid = threadIdx.x;
  const int dil = tid >> 2, nq = tid & 3;
  const int di  = di0 + dil;
  __shared__ float sDT[2][SCH][64];
  __shared__ float sXC[2][SCH][64];
  __shared__ float sZ [2][SCH][64];
  __shared__ float sBC[2][SCH][32];
  __shared__ u16  sY [SCH][64];

  float Arow[4];
  #pragma unroll
  for (int n = 0; n < 4; ++n) Arow[n] = -__expf(A_log[di * NST + nq * 4 + n]);
  const float Dv = Dsk[di];
  float h[4] = {0.f, 0.f, 0.f, 0.f};
  const size_t mb = (size_t)b * L_;

  const int r16 = tid >> 4, c16 = (tid & 15) * 4;   // 64-wide arrays, 2 rounds of 16 rows
  const int r8  = tid >> 3, c8  = (tid & 7) * 4;    // 32-wide BC, 1 round of 32 rows

  f32x4 pDT[2], pXC[2], pZ[2], pBC;
  auto issue = [&](int lb) {
    #pragma unroll
    for (int j = 0; j < 2; ++j) {
      int l = lb + r16 + j * 16;
      if (l < L_) {
        pDT[j] = *(const f32x4*)(dt + (mb + l) * DI_ + di0 + c16);
        pXC[j] = *(const f32x4*)(xc + (mb + l) * DI_ + di0 + c16);
        pZ[j]  = *(const f32x4*)(xz + (mb + l) * 1536 + DI_ + di0 + c16);
      } else { pDT[j] = {}; pXC[j] = {}; pZ[j] = {}; }
    }
    int l = lb + r8;
    if (l < L_) pBC = *(const f32x4*)(dbc + (mb + l) * 56 + 24 + c8);
    else        pBC = {};
  };
  auto store = [&](int buf) {
    #pragma unroll
    for (int j = 0; j < 2; ++j) {
      int row = r16 + j * 16;
      *(f32x4*)&sDT[buf][row][c16] = pDT[j];
      *(f32x4*)&sXC[buf][row][c16] = pXC[j];
      *(f32x4*)&sZ [buf][row][c16] = pZ[j];
    }
    *(f32x4*)&sBC[buf][r8][c8] = pBC;
  };

  issue(0); store(0); __syncthreads();
  const int nch = (L_ + SCH - 1) / SCH;   // 7
  for (int c = 0; c < nch; ++c) {
    const int lb = c * SCH;
    if (c + 1 < nch) issue(lb + SCH);     // global loads overlap compute below
    const int cur = c & 1;
    #pragma unroll 4
    for (int t = 0; t < SCH; ++t) {
      float dtc = sDT[cur][t][dil];
      float xcc = sXC[cur][t][dil];
      float dx = dtc * xcc;
      f32x4 Bv = *(const f32x4*)&sBC[cur][t][nq * 4];
      f32x4 Cv = *(const f32x4*)&sBC[cur][t][16 + nq * 4];
      float y = (nq == 0) ? Dv * xcc : 0.f;
      #pragma unroll
      for (int n = 0; n < 4; ++n) {
        float e = __expf(dtc * Arow[n]);
        h[n] = e * h[n] + dx * Bv[n];
        y += h[n] * Cv[n];
      }
      y += __shfl_xor(y, 1);
      y += __shfl_xor(y, 2);
      if (nq == 0) {
        float zc = sZ[cur][t][dil];
        float sz = zc / (1.f + __expf(-zc));
        sY[t][dil] = f2bf(y * sz);
      }
    }
    __syncthreads();
    #pragma unroll
    for (int j = 0; j < 4; ++j) {
      int id = tid + j * 256;
      int row = id >> 5, c2 = id & 31;
      int l = lb + row;
      if (l < L_)
        *((u32*)yb + ((mb + l) * DI_ + di0) / 2 + c2) = *((const u32*)&sY[row][0] + c2);
    }
    if (c + 1 < nch) store((c + 1) & 1);
    __syncthreads();
  }
}

// ---------------- final LN partial sums: grid (B_, 7), 28 rows each ----------------
__global__ __launch_bounds__(384)
void k_feat_part(const float* __restrict__ x, float* __restrict__ partial) {
  const int b = blockIdx.x, j = blockIdx.y, d = threadIdx.x;
  __shared__ float red[12];
  const int l0 = j * 28;
  float acc = 0.f;
  float v = x[((size_t)b * L_ + l0) * D_ + d];
  for (int l = l0; l < l0 + 28; ++l) {
    float vn = (l + 1 < l0 + 28) ? x[((size_t)b * L_ + l + 1) * D_ + d] : 0.f;
    float s = v, s2 = v * v;
    #pragma unroll
    for (int o = 32; o > 0; o >>= 1) { s += __shfl_xor(s, o); s2 += __shfl_xor(s2, o); }
    int wid = d >> 6;
    if ((d & 63) == 0) { red[wid] = s; red[6 + wid] = s2; }
    __syncthreads();
    float ts = 0.f, ts2 = 0.f;
    #pragma unroll
    for (int w = 0; w < 6; ++w) { ts += red[w]; ts2 += red[6 + w]; }
    float mu = ts * (1.f / (float)D_);
    float var = ts2 * (1.f / (float)D_) - mu * mu;
    acc += (v - mu) * rsqrtf(var + 1e-5f);
    __syncthreads();
    v = vn;
  }
  partial[((size_t)(b * 7 + j)) * D_ + d] = acc;
}

// ---------------- head (folds final-LN gamma/beta + mean) ----------------
__global__ __launch_bounds__(256)
void k_head(const float* __restrict__ partial, const float* __restrict__ g,
            const float* __restrict__ bt, const float* __restrict__ hw,
            const float* __restrict__ hb, float* __restrict__ out) {
  const int b = blockIdx.y;
  const int c = blockIdx.x * 256 + threadIdx.x;
  __shared__ float sf[D_];
  for (int i = threadIdx.x; i < D_; i += 256) {
    float s = 0.f;
    #pragma unroll
    for (int j = 0; j < 7; ++j) s += partial[((size_t)(b * 7 + j)) * D_ + i];
    sf[i] = g[i] * (s * (1.f / (float)L_)) + bt[i];
  }
  __syncthreads();
  if (c >= NC_) return;
  float acc = hb[c];
  for (int d = 0; d < D_; ++d) acc += sf[d] * hw[(size_t)d * NC_ + c];
  out[(size_t)b * NC_ + c] = acc;
}

// =====================================================================
extern "C" void kernel_launch(void* const* d_in, const int* in_sizes, int n_in,
                              void* d_out, int out_size, void* d_ws, size_t ws_size,
                              hipStream_t stream) {
  const float* x_in    = (const float*)d_in[0];
  const float* patch_w = (const float*)d_in[1];
  const float* patch_b = (const float*)d_in[2];
  const float* pos     = (const float*)d_in[3];
  const float* bn_g    = (const float*)d_in[4];
  const float* bn_b    = (const float*)d_in[5];
  const float* in_w    = (const float*)d_in[6];
  const float* conv_w  = (const float*)d_in[7];
  const float* conv_b  = (const float*)d_in[8];
  const float* xp_w    = (const float*)d_in[9];
  const float* dtp_w   = (const float*)d_in[10];
  const float* dtp_b   = (const float*)d_in[11];
  const float* A_log   = (const float*)d_in[12];
  const float* D_skip  = (const float*)d_in[13];
  const float* out_w   = (const float*)d_in[14];
  const float* norm_g  = (const float*)d_in[15];
  const float* norm_b  = (const float*)d_in[16];
  const float* head_w  = (const float*)d_in[17];
  const float* head_b  = (const float*)d_in[18];
  float* out = (float*)d_out;

  char* ws = (char*)d_ws;
  size_t off = 0;
  auto alloc = [&](size_t bytes) { size_t o = off; off += (bytes + 255) & ~(size_t)255; return o; };

  float* xbuf   = (float*)(ws + alloc((size_t)M_ * D_ * 4));
  u16*   hbuf   = (u16*)  (ws + alloc((size_t)M_ * D_ * 2));
  float* xzbuf  = (float*)(ws + alloc((size_t)M_ * 1536 * 4));
  float* xcbuf  = (float*)(ws + alloc((size_t)M_ * DI_ * 4));
  u16*   xcbb   = (u16*)  (ws + alloc((size_t)M_ * DI_ * 2));
  float* dbcbuf = (float*)(ws + alloc((size_t)M_ * 56 * 4));
  float* dtbuf  = (float*)(ws + alloc((size_t)M_ * DI_ * 4));   // aliased as im2col before loop
  u16*   ybuf   = (u16*)  (ws + alloc((size_t)M_ * DI_ * 2));
  float* partial= (float*)(ws + alloc((size_t)B_ * 7 * D_ * 4));
  u16*   in_wT  = (u16*)  (ws + alloc((size_t)DEPTH * 1536 * D_ * 2));
  u16*   xp_wT  = (u16*)  (ws + alloc((size_t)DEPTH * 56 * DI_ * 2));
  u16*   out_wT = (u16*)  (ws + alloc((size_t)DEPTH * D_ * DI_ * 2));
  u16*   pw_b   = (u16*)  (ws + alloc((size_t)D_ * 768 * 2));
  u16*   im2col = (u16*)dtbuf;

  dim3 tb(32, 8);
  k_transpose_bf16<<<dim3(48, 12, DEPTH), tb, 0, stream>>>(in_w,  in_wT,  D_, 1536);
  k_transpose_bf16<<<dim3(2, 24, DEPTH),  tb, 0, stream>>>(xp_w,  xp_wT,  DI_, 56);
  k_transpose_bf16<<<dim3(12, 24, DEPTH), tb, 0, stream>>>(out_w, out_wT, DI_, D_);
  k_convert_bf16<<<(D_ * 768 + 255) / 256, 256, 0, stream>>>(patch_w, pw_b, D_ * 768);

  k_im2col<<<(M_ * 768 + 255) / 256, 256, 0, stream>>>(x_in, im2col);
  k_gemm<64,128,2><<<dim3(M_ / 64, 3), 256, 0, stream>>>(im2col, pw_b, xbuf, D_, 768, patch_b, pos);

  for (int dp = 0; dp < DEPTH; ++dp) {
    const u16* iwt = in_wT  + (size_t)dp * 1536 * D_;
    const u16* xwt = xp_wT  + (size_t)dp * 56 * DI_;
    const u16* owt = out_wT + (size_t)dp * D_ * DI_;
    k_ln<<<M_, 384, 0, stream>>>(xbuf, bn_g + dp * D_, bn_b + dp * D_, hbuf);
    k_gemm<128,128,0><<<dim3(M_ / 128, 12), 256, 0, stream>>>(hbuf, iwt, xzbuf, 1536, D_, nullptr, nullptr);
    k_conv<<<(M_ * DI_ + 255) / 256, 256, 0, stream>>>(xzbuf, conv_w + (size_t)dp * DI_ * 4,
                                                       conv_b + dp * DI_, xcbuf, xcbb);
    k_gemm<32,64,0><<<dim3(M_ / 32, 1), 256, 0, stream>>>(xcbb, xwt, dbcbuf, 56, DI_, nullptr, nullptr);
    k_dt<<<dim3(M_ / 16, DI_ / 256), 256, 0, stream>>>(dbcbuf, dtp_w + (size_t)dp * R_ * DI_,
                                                       dtp_b + dp * DI_, dtbuf);
    k_scan<<<dim3(B_, DI_ / 64), 256, 0, stream>>>(dbcbuf, dtbuf, xcbuf, xzbuf,
                                                   A_log + (size_t)dp * DI_ * NST,
                                                   D_skip + dp * DI_, ybuf);
    k_gemm<64,128,1><<<dim3(M_ / 64, 3), 256, 0, stream>>>(ybuf, owt, xbuf, D_, DI_, nullptr, nullptr);
  }

  k_feat_part<<<dim3(B_, 7), 384, 0, stream>>>(xbuf, partial);
  k_head<<<dim3((NC_ + 255) / 256, B_), 256, 0, stream>>>(partial, norm_g, norm_b, head_w, head_b, out);
}